// Round 1
// baseline (142.547 us; speedup 1.0000x reference)
//
#include <hip/hip_runtime.h>

#define Bsz 64
#define Ssz 512
#define Hsz 768
#define Tsz 9

__device__ __forceinline__ float lane_bcast(float v, int l) {
    return __uint_as_float((unsigned)__builtin_amdgcn_readlane((int)__float_as_uint(v), l));
}

// ---------------- Kernel 1: emissions = enc @ fc_w^T + fc_b ----------------
// grid = B*S/4 blocks of 256 threads; one wave per (b,s) position.
__global__ __launch_bounds__(256) void emis_kernel(
    const float* __restrict__ x, const float* __restrict__ fcw,
    const float* __restrict__ fcb, float* __restrict__ em) {
    __shared__ __align__(16) float w[Tsz * Hsz];
    __shared__ float bias[Tsz];
    const int tid = threadIdx.x;
    for (int i = tid; i < Tsz * Hsz; i += 256) w[i] = fcw[i];
    if (tid < Tsz) bias[tid] = fcb[tid];
    __syncthreads();

    const int wave = tid >> 6, lane = tid & 63;
    const int pos = blockIdx.x * 4 + wave;  // < B*S
    const float4* xp4 = reinterpret_cast<const float4*>(x + (size_t)pos * Hsz);

    float4 xv[3];
#pragma unroll
    for (int k = 0; k < 3; ++k) xv[k] = xp4[k * 64 + lane];

    float out = 0.0f;
#pragma unroll
    for (int t = 0; t < Tsz; ++t) {
        float acc = 0.0f;
#pragma unroll
        for (int k = 0; k < 3; ++k) {
            const float4 wv =
                *reinterpret_cast<const float4*>(&w[t * Hsz + (k * 64 + lane) * 4]);
            acc += xv[k].x * wv.x + xv[k].y * wv.y + xv[k].z * wv.z + xv[k].w * wv.w;
        }
#pragma unroll
        for (int off = 32; off >= 1; off >>= 1) acc += __shfl_xor(acc, off, 64);
        if (lane == t) out = acc + bias[t];
    }
    if (lane < Tsz) em[(size_t)pos * Tsz + lane] = out;
}

// ---------------- Kernel 2: CRF per batch element ----------------
// grid = B blocks of 192 threads (3 waves: denominator / viterbi / numerator)
__global__ __launch_bounds__(192) void crf_kernel(
    const float* __restrict__ em, const int* __restrict__ labels,
    const int* __restrict__ mask, const float* __restrict__ start_t,
    const float* __restrict__ end_t, const float* __restrict__ trans,
    float* __restrict__ out_path /* = d_out + 1 */, float* __restrict__ ll) {
    __shared__ float sh_trans[Tsz * Tsz];
    __shared__ float sh_start[Tsz], sh_end[Tsz];
    __shared__ unsigned char bp[(Ssz - 1) * Tsz];
    __shared__ unsigned char gfun[64 * Tsz];
    __shared__ unsigned char entry[64];
    __shared__ float res_den, res_num;

    const int b = blockIdx.x;
    const int tid = threadIdx.x;
    if (tid < Tsz * Tsz) sh_trans[tid] = trans[tid];
    if (tid >= 128 && tid < 128 + Tsz) {
        sh_start[tid - 128] = start_t[tid - 128];
        sh_end[tid - 128] = end_t[tid - 128];
    }
    __syncthreads();

    const int wid = tid >> 6, lane = tid & 63;
    const float* em_b = em + (size_t)b * Ssz * Tsz;
    const int* mask_b = mask + b * Ssz;
    const int* lab_b = labels + b * Ssz;
    const int jc = lane < Tsz ? lane : Tsz - 1;

    if (wid == 0) {
        // ---- denominator: log-forward ----
        float tcol[Tsz];
#pragma unroll
        for (int i = 0; i < Tsz; ++i) tcol[i] = sh_trans[i * Tsz + jc];
        float alpha = sh_start[jc] + em_b[jc];
        float emv = em_b[Tsz + jc];
        int mkv = mask_b[1];
        for (int s = 1; s < Ssz; ++s) {
            const float em_cur = emv;
            const int mk_cur = mkv;
            const int sn = (s + 1 < Ssz) ? s + 1 : s;
            emv = em_b[sn * Tsz + jc];
            mkv = mask_b[sn];
            float a[Tsz];
#pragma unroll
            for (int i = 0; i < Tsz; ++i) a[i] = lane_bcast(alpha, i) + tcol[i];
            float m = a[0];
#pragma unroll
            for (int i = 1; i < Tsz; ++i) m = fmaxf(m, a[i]);
            float sum = 0.0f;
#pragma unroll
            for (int i = 0; i < Tsz; ++i) sum += __expf(a[i] - m);
            const float nxt = m + __logf(sum) + em_cur;
            if (mk_cur > 0) alpha = nxt;
        }
        float v = (lane < Tsz) ? alpha + sh_end[jc] : -1e30f;
        float mm = v;
#pragma unroll
        for (int off = 32; off >= 1; off >>= 1) mm = fmaxf(mm, __shfl_xor(mm, off, 64));
        float sm = (lane < Tsz) ? __expf(v - mm) : 0.0f;
#pragma unroll
        for (int off = 32; off >= 1; off >>= 1) sm += __shfl_xor(sm, off, 64);
        if (lane == 0) res_den = mm + __logf(sm);
    } else if (wid == 1) {
        // ---- viterbi forward ----
        float tcol[Tsz];
#pragma unroll
        for (int i = 0; i < Tsz; ++i) tcol[i] = sh_trans[i * Tsz + jc];
        float alpha = sh_start[jc] + em_b[jc];
        float emv = em_b[Tsz + jc];
        int mkv = mask_b[1];
        for (int s = 1; s < Ssz; ++s) {
            const float em_cur = emv;
            const int mk_cur = mkv;
            const int sn = (s + 1 < Ssz) ? s + 1 : s;
            emv = em_b[sn * Tsz + jc];
            mkv = mask_b[sn];
            float best = -1e30f;
            int bi = 0;
#pragma unroll
            for (int i = 0; i < Tsz; ++i) {
                const float vv = lane_bcast(alpha, i) + tcol[i];
                if (vv > best) { best = vv; bi = i; }  // strict > keeps FIRST max
            }
            if (lane < Tsz) {
                if (mk_cur > 0) {
                    alpha = best + em_cur;
                    bp[(s - 1) * Tsz + lane] = (unsigned char)bi;
                } else {
                    bp[(s - 1) * Tsz + lane] = (unsigned char)lane;  // identity
                }
            }
        }
        // last = argmax_j(alpha + end), first index on ties
        float v = (lane < Tsz) ? alpha + sh_end[jc] : -1e30f;
        int idx = lane;
#pragma unroll
        for (int off = 32; off >= 1; off >>= 1) {
            const float ov = __shfl_xor(v, off, 64);
            const int oi = __shfl_xor(idx, off, 64);
            if (ov > v || (ov == v && oi < idx)) { v = ov; idx = oi; }
        }
        const int last = idx;

        // ---- backtrace, chunked (64 chunks of <=8 steps) ----
        const int k_lo = lane * 8;
        const int k_hi = min(k_lo + 7, Ssz - 2);
        int xf[Tsz];
#pragma unroll
        for (int t = 0; t < Tsz; ++t) xf[t] = t;
        for (int k = k_hi; k >= k_lo; --k) {
#pragma unroll
            for (int t = 0; t < Tsz; ++t) xf[t] = bp[k * Tsz + xf[t]];
        }
#pragma unroll
        for (int t = 0; t < Tsz; ++t) gfun[lane * Tsz + t] = (unsigned char)xf[t];

        if (lane == 0) {
            int t = last;
            for (int l = 63; l >= 0; --l) {
                entry[l] = (unsigned char)t;
                t = gfun[l * Tsz + t];
            }
            out_path[b * Ssz + (Ssz - 1)] = (float)last;
        }
        int t = entry[lane];
        for (int k = k_hi; k >= k_lo; --k) {
            t = bp[k * Tsz + t];
            out_path[b * Ssz + k] = (float)t;
        }
    } else {
        // ---- numerator: gold path score ----
        float part = 0.0f;
        for (int s = 1 + lane; s < Ssz; s += 64) {
            const int mk = mask_b[s];
            if (mk > 0) {
                const int tg = lab_b[s];
                int p = s - 1;
                while (p > 0 && mask_b[p] == 0) --p;
                const int pv = lab_b[p];
                part += sh_trans[pv * Tsz + tg] + em_b[s * Tsz + tg];
            }
        }
#pragma unroll
        for (int off = 32; off >= 1; off >>= 1) part += __shfl_xor(part, off, 64);
        if (lane == 0) {
            const int tg0 = lab_b[0];
            float total = part + sh_start[tg0] + em_b[tg0];
            int p = Ssz - 1;
            while (p > 0 && mask_b[p] == 0) --p;
            total += sh_end[lab_b[p]];
            res_num = total;
        }
    }
    __syncthreads();
    if (tid == 0) ll[b] = res_num - res_den;
}

// ---------------- Kernel 3: final loss reduce + lengths ----------------
__global__ __launch_bounds__(64) void fin_kernel(const float* __restrict__ ll,
                                                 const int* __restrict__ lengths,
                                                 float* __restrict__ dout) {
    const int lane = threadIdx.x;
    float v = ll[lane];
#pragma unroll
    for (int off = 32; off >= 1; off >>= 1) v += __shfl_xor(v, off, 64);
    if (lane == 0) dout[0] = -v / (float)Bsz;
    dout[1 + Bsz * Ssz + lane] = (float)lengths[lane];
}

extern "C" void kernel_launch(void* const* d_in, const int* in_sizes, int n_in,
                              void* d_out, int out_size, void* d_ws, size_t ws_size,
                              hipStream_t stream) {
    const float* enc    = (const float*)d_in[0];
    const int*   labels = (const int*)d_in[1];
    const int*   mask   = (const int*)d_in[2];
    const int*   lengths= (const int*)d_in[3];
    const float* fcw    = (const float*)d_in[4];
    const float* fcb    = (const float*)d_in[5];
    const float* startt = (const float*)d_in[6];
    const float* endt   = (const float*)d_in[7];
    const float* trans  = (const float*)d_in[8];

    float* out = (float*)d_out;
    float* em  = (float*)d_ws;                       // B*S*T floats
    float* ll  = em + (size_t)Bsz * Ssz * Tsz;       // B floats

    emis_kernel<<<Bsz * Ssz / 4, 256, 0, stream>>>(enc, fcw, fcb, em);
    crf_kernel<<<Bsz, 192, 0, stream>>>(em, labels, mask, startt, endt, trans,
                                        out + 1, ll);
    fin_kernel<<<1, 64, 0, stream>>>(ll, lengths, out);
}